// Round 3
// baseline (289.866 us; speedup 1.0000x reference)
//
#include <hip/hip_runtime.h>
#include <stdint.h>

// Problem constants (from reference): B=4, N=8192, D=512, H=8, Dh=64
#define SEQ      8192
#define BATCH    4
#define DIM      512
#define MROWS    32768      // BATCH*SEQ
#define CHUNK    64
#define NCHUNK   128        // SEQ / CHUNK
#define NCHAN    2048       // BATCH * DIM

typedef unsigned short ushort;
typedef unsigned int   uint;
typedef __bf16 bf16x8 __attribute__((ext_vector_type(8)));
typedef float  f32x4  __attribute__((ext_vector_type(4)));

__device__ __forceinline__ ushort f2bf(float f) {
    unsigned u = __float_as_uint(f);
    unsigned r = (u + 0x7fffu + ((u >> 16) & 1u)) >> 16;   // RNE
    return (ushort)r;
}
__device__ __forceinline__ float bf2f(ushort v) {
    return __uint_as_float(((unsigned)v) << 16);
}

// ---------------- fp32 -> bf16 convert (vectorized x4) ----------------
__global__ void f32_to_bf16_kernel(const float* __restrict__ in,
                                   ushort* __restrict__ out, int n4) {
    int i = blockIdx.x * blockDim.x + threadIdx.x;
    if (i >= n4) return;
    float4 v = ((const float4*)in)[i];
    ushort4 r;
    r.x = f2bf(v.x); r.y = f2bf(v.y); r.z = f2bf(v.z); r.w = f2bf(v.w);
    ((ushort4*)out)[i] = r;
}

// both weight matrices in one launch; outputs are contiguous in ws
__global__ void weights_to_bf16_kernel(const float* __restrict__ w_in,
                                       const float* __restrict__ w_out,
                                       ushort* __restrict__ dst, int n4each) {
    int i = blockIdx.x * blockDim.x + threadIdx.x;
    if (i >= 2 * n4each) return;
    const float4* src = (i < n4each) ? (const float4*)w_in
                                     : (const float4*)w_out - n4each;
    float4 v = src[i];
    ushort4 r;
    r.x = f2bf(v.x); r.y = f2bf(v.y); r.z = f2bf(v.z); r.w = f2bf(v.w);
    ((ushort4*)dst)[i] = r;
}

// ---------------- bf16 GEMM, NO-LDS direct-load variant ----------------
// C[m,n] = sum_k A[m,k]*Bw[n,k] + bias[n]
// A: [M,K] bf16 row-major, Bw: [N,K] bf16 row-major.
// 128x128 block tile, 4 waves (2x2), each wave 64x64 = 4x4 mfma_16x16x32_bf16.
// K=512 -> per-iter operand footprint is 8KB(A)+8KB(B): L1-resident, so MFMA
// fragments are loaded straight from global as dwordx4 (16B/lane, 64B segs).
// No LDS, no barriers -> compiler pipelines VMEM across K-iters with vmcnt.
// Operands swapped in the MFMA so acc layout is m=lane&15, n=quad*4+reg
// -> float4/ushort4 epilogue stores.
template <bool OUT_BF16>
__global__ __launch_bounds__(256, 3) void gemm_bt_kernel(
        const ushort* __restrict__ A, const ushort* __restrict__ Bw,
        const float* __restrict__ bias, void* __restrict__ Cout,
        int M, int N, int K)
{
    const int tid  = threadIdx.x;
    const int lane = tid & 63;
    const int wave = tid >> 6;
    const int wr = wave >> 1, wc = wave & 1;
    const int bm = blockIdx.y, bn = blockIdx.x;
    const int quad = lane >> 4, r16 = lane & 15;

    // per-lane fragment base pointers (row r16 within each 16-row tile)
    const ushort* Abase = A  + (size_t)(bm * 128 + wr * 64 + r16) * K + quad * 8;
    const ushort* Bbase = Bw + (size_t)(bn * 128 + wc * 64 + r16) * K + quad * 8;
    const size_t tstride = (size_t)16 * K;   // 16 rows

    f32x4 acc[4][4];
    #pragma unroll
    for (int i = 0; i < 4; i++)
        #pragma unroll
        for (int j = 0; j < 4; j++)
            acc[i][j] = f32x4{0.f, 0.f, 0.f, 0.f};

    #pragma unroll 2
    for (int k0 = 0; k0 < K; k0 += 32) {
        bf16x8 af[4], bfr[4];
        #pragma unroll
        for (int i = 0; i < 4; i++)
            af[i]  = *(const bf16x8*)(Abase + i * tstride + k0);
        #pragma unroll
        for (int j = 0; j < 4; j++)
            bfr[j] = *(const bf16x8*)(Bbase + j * tstride + k0);
        #pragma unroll
        for (int i = 0; i < 4; i++)
            #pragma unroll
            for (int j = 0; j < 4; j++)
                acc[i][j] = __builtin_amdgcn_mfma_f32_16x16x32_bf16(
                                bfr[j], af[i], acc[i][j], 0, 0, 0);  // swapped
    }

    // epilogue: transposed layout -> m = lane&15 (per i-tile), n = quad*4+reg
    #pragma unroll
    for (int i = 0; i < 4; i++) {
        const int m = bm * 128 + wr * 64 + i * 16 + r16;
        #pragma unroll
        for (int j = 0; j < 4; j++) {
            const int n0 = bn * 128 + wc * 64 + j * 16 + quad * 4;
            const float4 bv = *(const float4*)&bias[n0];
            float v0 = acc[i][j][0] + bv.x;
            float v1 = acc[i][j][1] + bv.y;
            float v2 = acc[i][j][2] + bv.z;
            float v3 = acc[i][j][3] + bv.w;
            size_t idx = (size_t)m * N + n0;
            if (OUT_BF16) {
                ushort4 r;
                r.x = f2bf(v0); r.y = f2bf(v1); r.z = f2bf(v2); r.w = f2bf(v3);
                *(ushort4*)&((ushort*)Cout)[idx] = r;
            } else {
                *(float4*)&((float*)Cout)[idx] = make_float4(v0, v1, v2, v3);
            }
        }
    }
}

// ---------------- chunked linear-recurrence scan ----------------
// z[t] = c*z[t-1] + alpha*(xp[t]-xp[t-1]),  z[-1]=xp[-1]=init_state[h,dh]
// Each thread owns 2 adjacent channels (bf16x2 = uint loads/stores).
// Phase A (WRITE_Z=false): per-chunk local scan with zero seed -> Lfin carry.
// Phase C (WRITE_Z=true):  re-run seeded with exact boundary state -> z (bf16).
template <bool WRITE_Z>
__global__ void scan_kernel(const ushort* __restrict__ xp,
                            const float* __restrict__ alpha_param,
                            const float* __restrict__ init_state,
                            const float* __restrict__ Zin,
                            float* __restrict__ Lfin,
                            ushort* __restrict__ zout)
{
    const int tid   = threadIdx.x;
    const int chunk = blockIdx.x;          // 0..NCHUNK-1
    const int b     = blockIdx.y;          // 0..3
    const int d0    = tid * 2;             // 0..510 ; d = h*64+dh
    const int h     = d0 >> 6;

    const float alpha = 1.0f / (1.0f + expf(-alpha_param[h]));
    const float cdec  = 1.0f - alpha;
    const int   t0    = chunk * CHUNK;
    const size_t baseRow = (size_t)b * SEQ;
    const int ch0 = b * DIM + d0;

    float prev0, prev1;
    if (chunk == 0) {
        prev0 = init_state[d0]; prev1 = init_state[d0 + 1];
    } else {
        uint u = *(const uint*)&xp[(baseRow + t0 - 1) * DIM + d0];
        prev0 = bf2f((ushort)(u & 0xffffu)); prev1 = bf2f((ushort)(u >> 16));
    }
    float z0 = 0.f, z1 = 0.f;
    if (WRITE_Z) {
        z0 = Zin[(size_t)ch0 * NCHUNK + chunk];
        z1 = Zin[(size_t)(ch0 + 1) * NCHUNK + chunk];
    }

    const ushort* p = xp + (baseRow + t0) * DIM + d0;
    ushort* q = WRITE_Z ? (zout + (baseRow + t0) * DIM + d0) : nullptr;
    #pragma unroll 8
    for (int t = 0; t < CHUNK; ++t) {
        uint u = *(const uint*)&p[(size_t)t * DIM];
        float cur0 = bf2f((ushort)(u & 0xffffu));
        float cur1 = bf2f((ushort)(u >> 16));
        z0 = cdec * z0 + alpha * (cur0 - prev0);
        z1 = cdec * z1 + alpha * (cur1 - prev1);
        prev0 = cur0; prev1 = cur1;
        if (WRITE_Z) {
            uint w = (uint)f2bf(z0) | ((uint)f2bf(z1) << 16);
            *(uint*)&q[(size_t)t * DIM] = w;
        }
    }
    if (!WRITE_Z) {
        Lfin[(size_t)ch0 * NCHUNK + chunk]       = z0;
        Lfin[(size_t)(ch0 + 1) * NCHUNK + chunk] = z1;
    }
}

// Phase B: per-channel carry scan across the NCHUNK chunks.
__global__ void scan_fix_kernel(const float* __restrict__ Lfin,
                                const float* __restrict__ alpha_param,
                                const float* __restrict__ init_state,
                                float* __restrict__ Zin)
{
    int ch = blockIdx.x * blockDim.x + threadIdx.x;   // 0..2047 = b*512+d
    if (ch >= NCHAN) return;
    int d = ch & (DIM - 1);
    int h = d >> 6;
    float alpha = 1.0f / (1.0f + expf(-alpha_param[h]));
    float c = 1.0f - alpha;
    float cT = c;
    #pragma unroll
    for (int i = 0; i < 6; i++) cT *= cT;             // c^64, exact squarings
    float Z = init_state[d];
    const float* L = Lfin + (size_t)ch * NCHUNK;
    float*      Zp = Zin  + (size_t)ch * NCHUNK;
    for (int i = 0; i < NCHUNK; i++) { Zp[i] = Z; Z = L[i] + cT * Z; }
}

extern "C" void kernel_launch(void* const* d_in, const int* in_sizes, int n_in,
                              void* d_out, int out_size, void* d_ws, size_t ws_size,
                              hipStream_t stream) {
    const float* x           = (const float*)d_in[0];
    const float* W_in        = (const float*)d_in[1];
    const float* b_in        = (const float*)d_in[2];
    const float* W_out       = (const float*)d_in[3];
    const float* b_out       = (const float*)d_in[4];
    const float* init_state  = (const float*)d_in[5];
    const float* alpha_param = (const float*)d_in[6];
    float* out = (float*)d_out;

    // workspace layout (ushort units); z_bf aliases x_bf (x dead after GEMM1)
    ushort* x_bf    = (ushort*)d_ws;                        // 16,777,216
    ushort* win_bf  = x_bf   + (size_t)MROWS * DIM;         //    262,144
    ushort* wout_bf = win_bf + (size_t)DIM * DIM;           //    262,144
    ushort* xp_bf   = wout_bf + (size_t)DIM * DIM;          // 16,777,216
    ushort* z_bf    = x_bf;                                 // alias
    float*  Lfin    = (float*)(xp_bf + (size_t)MROWS * DIM);
    float*  Zin     = Lfin + (size_t)NCHAN * NCHUNK;

    const int nx4 = (MROWS * DIM) / 4;        // 4,194,304
    const int nw4 = (DIM * DIM) / 4;          //    65,536
    f32_to_bf16_kernel<<<(nx4 + 255) / 256, 256, 0, stream>>>(x, x_bf, nx4);
    weights_to_bf16_kernel<<<(2 * nw4 + 255) / 256, 256, 0, stream>>>(
        W_in, W_out, win_bf, nw4);

    dim3 ggrid(DIM / 128, MROWS / 128);       // (4, 256)
    gemm_bt_kernel<true><<<ggrid, 256, 0, stream>>>(
        x_bf, win_bf, b_in, (void*)xp_bf, MROWS, DIM, DIM);

    dim3 sgrid(NCHUNK, BATCH);                // (128, 4)
    scan_kernel<false><<<sgrid, 256, 0, stream>>>(
        xp_bf, alpha_param, init_state, nullptr, Lfin, nullptr);
    scan_fix_kernel<<<NCHAN / 256, 256, 0, stream>>>(
        Lfin, alpha_param, init_state, Zin);
    scan_kernel<true><<<sgrid, 256, 0, stream>>>(
        xp_bf, alpha_param, init_state, Zin, nullptr, z_bf);

    gemm_bt_kernel<false><<<ggrid, 256, 0, stream>>>(
        z_bf, wout_bf, b_out, (void*)out, MROWS, DIM, DIM);
}

// Round 4
// 219.622 us; speedup vs baseline: 1.3198x; 1.3198x over previous
//
#include <hip/hip_runtime.h>
#include <stdint.h>

// Problem constants (from reference): B=4, N=8192, D=512, H=8, Dh=64
#define SEQ      8192
#define BATCH    4
#define DIM      512
#define MROWS    32768      // BATCH*SEQ
#define CHUNK    64
#define NCHUNK   128        // SEQ / CHUNK
#define NCHAN    2048       // BATCH * DIM

typedef unsigned short ushort;
typedef unsigned int   uint;
typedef __bf16 bf16x8 __attribute__((ext_vector_type(8)));
typedef float  f32x4  __attribute__((ext_vector_type(4)));

__device__ __forceinline__ ushort f2bf(float f) {
    unsigned u = __float_as_uint(f);
    unsigned r = (u + 0x7fffu + ((u >> 16) & 1u)) >> 16;   // RNE
    return (ushort)r;
}
__device__ __forceinline__ float bf2f(ushort v) {
    return __uint_as_float(((unsigned)v) << 16);
}

// ---------------- fp32 -> bf16 convert (vectorized x4) ----------------
__global__ void f32_to_bf16_kernel(const float* __restrict__ in,
                                   ushort* __restrict__ out, int n4) {
    int i = blockIdx.x * blockDim.x + threadIdx.x;
    if (i >= n4) return;
    float4 v = ((const float4*)in)[i];
    ushort4 r;
    r.x = f2bf(v.x); r.y = f2bf(v.y); r.z = f2bf(v.z); r.w = f2bf(v.w);
    ((ushort4*)out)[i] = r;
}

// both weight matrices in one launch; outputs are contiguous in ws
__global__ void weights_to_bf16_kernel(const float* __restrict__ w_in,
                                       const float* __restrict__ w_out,
                                       ushort* __restrict__ dst, int n4each) {
    int i = blockIdx.x * blockDim.x + threadIdx.x;
    if (i >= 2 * n4each) return;
    const float4* src = (i < n4each) ? (const float4*)w_in
                                     : (const float4*)w_out - n4each;
    float4 v = src[i];
    ushort4 r;
    r.x = f2bf(v.x); r.y = f2bf(v.y); r.z = f2bf(v.z); r.w = f2bf(v.w);
    ((ushort4*)dst)[i] = r;
}

// ---------------- bf16 GEMM, double-buffered LDS, ONE barrier per K-iter ----
// C[m,n] = sum_k A[m,k]*Bw[n,k] + bias[n]
// A: [M,K] bf16 row-major, Bw: [N,K] bf16 row-major (x @ W^T form).
// 128x128 tile, 4 waves (2x2), each wave 64x64 = 4x4 mfma_16x16x32_bf16.
// K-loop: after each barrier, issue GLDS for iter k+1 into the OTHER buffer,
// then ds_read+MFMA from the current one. The barrier's implicit vmcnt(0)
// drain thus lands after a full compute phase -> staging overlaps MFMA.
// (R3 lesson: MFMA operands direct from global = latency-bound, 74 us.)
#define GLDS(g, l) __builtin_amdgcn_global_load_lds(                        \
        (const __attribute__((address_space(1))) void*)(g),                 \
        (__attribute__((address_space(3))) void*)(l), 16, 0, 0)

template <bool OUT_BF16>
__global__ __launch_bounds__(256, 2) void gemm_bt_kernel(
        const ushort* __restrict__ A, const ushort* __restrict__ Bw,
        const float* __restrict__ bias, void* __restrict__ Cout,
        int M, int N, int K)
{
    __shared__ __align__(16) ushort As[2][128 * 32];
    __shared__ __align__(16) ushort Bs[2][128 * 32];

    const int tid  = threadIdx.x;
    const int lane = tid & 63;
    const int wave = tid >> 6;
    const int wr = wave >> 1, wc = wave & 1;
    const int bm = blockIdx.y, bn = blockIdx.x;

    // staging map: thread -> (row = tid/4, 16B k-chunk = tid%4); LDS dst = tid*16B
    const int srow = tid >> 2;
    const int sk   = tid & 3;
    const ushort* Ag = A  + (size_t)(bm * 128 + srow) * K + sk * 8;
    const ushort* Bg = Bw + (size_t)(bn * 128 + srow) * K + sk * 8;
    const size_t rowHalf = (size_t)64 * K;   // +64 rows (elements)

    f32x4 acc[4][4];
    #pragma unroll
    for (int i = 0; i < 4; i++)
        #pragma unroll
        for (int j = 0; j < 4; j++)
            acc[i][j] = f32x4{0.f, 0.f, 0.f, 0.f};

    const int quad = lane >> 4, r16 = lane & 15;
    const int nIter = K / 32;

    // prologue: stage iter 0 into buffer 0
    {
        ushort* Al = &As[0][tid * 8];
        ushort* Bl = &Bs[0][tid * 8];
        GLDS(Ag,           Al);
        GLDS(Ag + rowHalf, Al + 2048);
        GLDS(Bg,           Bl);
        GLDS(Bg + rowHalf, Bl + 2048);
    }

    int buf = 0;
    for (int k = 0; k < nIter; ++k) {
        __syncthreads();   // drains vmcnt: buf ready; prev reads of buf^1 done

        if (k + 1 < nIter) {
            const int ko = (k + 1) * 32;
            ushort* Al = &As[buf ^ 1][tid * 8];
            ushort* Bl = &Bs[buf ^ 1][tid * 8];
            GLDS(Ag + ko,           Al);
            GLDS(Ag + ko + rowHalf, Al + 2048);
            GLDS(Bg + ko,           Bl);
            GLDS(Bg + ko + rowHalf, Bl + 2048);
        }

        bf16x8 af[4], bfr[4];
        #pragma unroll
        for (int i = 0; i < 4; i++)
            af[i] = *(const bf16x8*)&As[buf][(wr * 64 + i * 16 + r16) * 32 + quad * 8];
        #pragma unroll
        for (int j = 0; j < 4; j++)
            bfr[j] = *(const bf16x8*)&Bs[buf][(wc * 64 + j * 16 + r16) * 32 + quad * 8];

        #pragma unroll
        for (int i = 0; i < 4; i++)
            #pragma unroll
            for (int j = 0; j < 4; j++)
                acc[i][j] = __builtin_amdgcn_mfma_f32_16x16x32_bf16(
                                bfr[j], af[i], acc[i][j], 0, 0, 0);  // swapped
        buf ^= 1;
    }

    // epilogue: transposed layout -> m = lane&15 (per i-tile), n = quad*4+reg
    #pragma unroll
    for (int i = 0; i < 4; i++) {
        const int m = bm * 128 + wr * 64 + i * 16 + r16;
        #pragma unroll
        for (int j = 0; j < 4; j++) {
            const int n0 = bn * 128 + wc * 64 + j * 16 + quad * 4;
            const float4 bv = *(const float4*)&bias[n0];
            float v0 = acc[i][j][0] + bv.x;
            float v1 = acc[i][j][1] + bv.y;
            float v2 = acc[i][j][2] + bv.z;
            float v3 = acc[i][j][3] + bv.w;
            size_t idx = (size_t)m * N + n0;
            if (OUT_BF16) {
                ushort4 r;
                r.x = f2bf(v0); r.y = f2bf(v1); r.z = f2bf(v2); r.w = f2bf(v3);
                *(ushort4*)&((ushort*)Cout)[idx] = r;
            } else {
                *(float4*)&((float*)Cout)[idx] = make_float4(v0, v1, v2, v3);
            }
        }
    }
}

// ---------------- chunked linear-recurrence scan ----------------
// z[t] = c*z[t-1] + alpha*(xp[t]-xp[t-1]),  z[-1]=xp[-1]=init_state[h,dh]
// Each thread owns 2 adjacent channels (bf16x2 = uint loads/stores).
template <bool WRITE_Z>
__global__ void scan_kernel(const ushort* __restrict__ xp,
                            const float* __restrict__ alpha_param,
                            const float* __restrict__ init_state,
                            const float* __restrict__ Zin,
                            float* __restrict__ Lfin,
                            ushort* __restrict__ zout)
{
    const int tid   = threadIdx.x;
    const int chunk = blockIdx.x;          // 0..NCHUNK-1
    const int b     = blockIdx.y;          // 0..3
    const int d0    = tid * 2;             // 0..510 ; d = h*64+dh
    const int h     = d0 >> 6;

    const float alpha = 1.0f / (1.0f + expf(-alpha_param[h]));
    const float cdec  = 1.0f - alpha;
    const int   t0    = chunk * CHUNK;
    const size_t baseRow = (size_t)b * SEQ;
    const int ch0 = b * DIM + d0;

    float prev0, prev1;
    if (chunk == 0) {
        prev0 = init_state[d0]; prev1 = init_state[d0 + 1];
    } else {
        uint u = *(const uint*)&xp[(baseRow + t0 - 1) * DIM + d0];
        prev0 = bf2f((ushort)(u & 0xffffu)); prev1 = bf2f((ushort)(u >> 16));
    }
    float z0 = 0.f, z1 = 0.f;
    if (WRITE_Z) {
        z0 = Zin[(size_t)ch0 * NCHUNK + chunk];
        z1 = Zin[(size_t)(ch0 + 1) * NCHUNK + chunk];
    }

    const ushort* p = xp + (baseRow + t0) * DIM + d0;
    ushort* q = WRITE_Z ? (zout + (baseRow + t0) * DIM + d0) : nullptr;
    #pragma unroll 8
    for (int t = 0; t < CHUNK; ++t) {
        uint u = *(const uint*)&p[(size_t)t * DIM];
        float cur0 = bf2f((ushort)(u & 0xffffu));
        float cur1 = bf2f((ushort)(u >> 16));
        z0 = cdec * z0 + alpha * (cur0 - prev0);
        z1 = cdec * z1 + alpha * (cur1 - prev1);
        prev0 = cur0; prev1 = cur1;
        if (WRITE_Z) {
            uint w = (uint)f2bf(z0) | ((uint)f2bf(z1) << 16);
            *(uint*)&q[(size_t)t * DIM] = w;
        }
    }
    if (!WRITE_Z) {
        Lfin[(size_t)ch0 * NCHUNK + chunk]       = z0;
        Lfin[(size_t)(ch0 + 1) * NCHUNK + chunk] = z1;
    }
}

// Phase B: per-channel carry scan across the NCHUNK chunks.
__global__ void scan_fix_kernel(const float* __restrict__ Lfin,
                                const float* __restrict__ alpha_param,
                                const float* __restrict__ init_state,
                                float* __restrict__ Zin)
{
    int ch = blockIdx.x * blockDim.x + threadIdx.x;   // 0..2047 = b*512+d
    if (ch >= NCHAN) return;
    int d = ch & (DIM - 1);
    int h = d >> 6;
    float alpha = 1.0f / (1.0f + expf(-alpha_param[h]));
    float c = 1.0f - alpha;
    float cT = c;
    #pragma unroll
    for (int i = 0; i < 6; i++) cT *= cT;             // c^64, exact squarings
    float Z = init_state[d];
    const float* L = Lfin + (size_t)ch * NCHUNK;
    float*      Zp = Zin  + (size_t)ch * NCHUNK;
    for (int i = 0; i < NCHUNK; i++) { Zp[i] = Z; Z = L[i] + cT * Z; }
}

extern "C" void kernel_launch(void* const* d_in, const int* in_sizes, int n_in,
                              void* d_out, int out_size, void* d_ws, size_t ws_size,
                              hipStream_t stream) {
    const float* x           = (const float*)d_in[0];
    const float* W_in        = (const float*)d_in[1];
    const float* b_in        = (const float*)d_in[2];
    const float* W_out       = (const float*)d_in[3];
    const float* b_out       = (const float*)d_in[4];
    const float* init_state  = (const float*)d_in[5];
    const float* alpha_param = (const float*)d_in[6];
    float* out = (float*)d_out;

    // workspace layout (ushort units); z_bf aliases x_bf (x dead after GEMM1)
    ushort* x_bf    = (ushort*)d_ws;                        // 16,777,216
    ushort* win_bf  = x_bf   + (size_t)MROWS * DIM;         //    262,144
    ushort* wout_bf = win_bf + (size_t)DIM * DIM;           //    262,144
    ushort* xp_bf   = wout_bf + (size_t)DIM * DIM;          // 16,777,216
    ushort* z_bf    = x_bf;                                 // alias
    float*  Lfin    = (float*)(xp_bf + (size_t)MROWS * DIM);
    float*  Zin     = Lfin + (size_t)NCHAN * NCHUNK;

    const int nx4 = (MROWS * DIM) / 4;        // 4,194,304
    const int nw4 = (DIM * DIM) / 4;          //    65,536
    f32_to_bf16_kernel<<<(nx4 + 255) / 256, 256, 0, stream>>>(x, x_bf, nx4);
    weights_to_bf16_kernel<<<(2 * nw4 + 255) / 256, 256, 0, stream>>>(
        W_in, W_out, win_bf, nw4);

    dim3 ggrid(DIM / 128, MROWS / 128);       // (4, 256)
    gemm_bt_kernel<true><<<ggrid, 256, 0, stream>>>(
        x_bf, win_bf, b_in, (void*)xp_bf, MROWS, DIM, DIM);

    dim3 sgrid(NCHUNK, BATCH);                // (128, 4)
    scan_kernel<false><<<sgrid, 256, 0, stream>>>(
        xp_bf, alpha_param, init_state, nullptr, Lfin, nullptr);
    scan_fix_kernel<<<NCHAN / 256, 256, 0, stream>>>(
        Lfin, alpha_param, init_state, Zin);
    scan_kernel<true><<<sgrid, 256, 0, stream>>>(
        xp_bf, alpha_param, init_state, Zin, nullptr, z_bf);

    gemm_bt_kernel<false><<<ggrid, 256, 0, stream>>>(
        z_bf, wout_bf, b_out, (void*)out, MROWS, DIM, DIM);
}

// Round 5
// 214.088 us; speedup vs baseline: 1.3540x; 1.0258x over previous
//
#include <hip/hip_runtime.h>
#include <stdint.h>

// Problem constants (from reference): B=4, N=8192, D=512, H=8, Dh=64
#define SEQ      8192
#define BATCH    4
#define DIM      512
#define MROWS    32768      // BATCH*SEQ
#define CHUNK    64
#define NCHUNK   128        // SEQ / CHUNK
#define NCHAN    2048       // BATCH * DIM

typedef unsigned short ushort;
typedef unsigned int   uint;
typedef __bf16 bf16x8 __attribute__((ext_vector_type(8)));
typedef float  f32x4  __attribute__((ext_vector_type(4)));
typedef ushort usx8   __attribute__((ext_vector_type(8)));

__device__ __forceinline__ ushort f2bf(float f) {
    unsigned u = __float_as_uint(f);
    unsigned r = (u + 0x7fffu + ((u >> 16) & 1u)) >> 16;   // RNE
    return (ushort)r;
}
__device__ __forceinline__ float bf2f(ushort v) {
    return __uint_as_float(((unsigned)v) << 16);
}

// both weight matrices in one launch; outputs are contiguous in ws
__global__ void weights_to_bf16_kernel(const float* __restrict__ w_in,
                                       const float* __restrict__ w_out,
                                       ushort* __restrict__ dst, int n4each) {
    int i = blockIdx.x * blockDim.x + threadIdx.x;
    if (i >= 2 * n4each) return;
    const float4* src = (i < n4each) ? (const float4*)w_in
                                     : (const float4*)w_out - n4each;
    float4 v = src[i];
    ushort4 r;
    r.x = f2bf(v.x); r.y = f2bf(v.y); r.z = f2bf(v.z); r.w = f2bf(v.w);
    ((ushort4*)dst)[i] = r;
}

// ---------------- bf16 GEMM, 128x256 tile, 8 waves, dbuf, 1 barrier/iter ----
// C[m,n] = sum_k A[m,k]*Bw[n,k] + bias[n]
// A_F32: A is fp32 in global; staged via VGPR (dwordx4 loads) + cvt + ds_write
//        -> fuses the x fp32->bf16 conversion into GEMM1 (kills a 16us pass).
// else:  A staged via global_load_lds (bf16).
// B (weights, 0.5 MB, L2-resident) always staged via global_load_lds.
// 8 waves as 2(m) x 4(n); each wave 64x64 = 4x4 mfma_16x16x32_bf16.
// Swapped MFMA operands -> acc m=lane&15, n=quad*4+reg -> float4 epilogue.
#define GLDS(g, l) __builtin_amdgcn_global_load_lds(                        \
        (const __attribute__((address_space(1))) void*)(g),                 \
        (__attribute__((address_space(3))) void*)(l), 16, 0, 0)

template <bool A_F32, bool OUT_BF16>
__global__ __launch_bounds__(512, 4) void gemm_kernel(
        const void* __restrict__ Aptr, const ushort* __restrict__ Bw,
        const float* __restrict__ bias, void* __restrict__ Cout,
        int M, int N, int K)
{
    __shared__ __align__(16) ushort As[2][128 * 32];   //  8 KB each
    __shared__ __align__(16) ushort Bs[2][256 * 32];   // 16 KB each

    const int tid  = threadIdx.x;           // 0..511
    const int lane = tid & 63;
    const int wave = tid >> 6;              // 0..7
    const int wr = wave >> 2, wc = wave & 3;
    const int bm = blockIdx.y, bn = blockIdx.x;
    const int quad = lane >> 4, r16 = lane & 15;

    // staging map: thread -> A row = tid>>2 (0..127), k-off = (tid&3)*8
    const int srow = tid >> 2;
    const int skoff = (tid & 3) * 8;
    const float*  Ag32 = (const float*) Aptr + (size_t)(bm * 128 + srow) * K + skoff;
    const ushort* Ag16 = (const ushort*)Aptr + (size_t)(bm * 128 + srow) * K + skoff;
    // B rows: chunk c in {0,1}: row = c*128 + srow
    const ushort* Bg0 = Bw + (size_t)(bn * 256 + srow) * K + skoff;
    const ushort* Bg1 = Bg0 + (size_t)128 * K;

    f32x4 acc[4][4];
    #pragma unroll
    for (int i = 0; i < 4; i++)
        #pragma unroll
        for (int j = 0; j < 4; j++)
            acc[i][j] = f32x4{0.f, 0.f, 0.f, 0.f};

    const int nIter = K / 32;

    // ---- stage iteration k0 into buffer b ----
    auto stageB = [&](int k0, int b) {
        GLDS(Bg0 + k0, &Bs[b][tid * 8]);
        GLDS(Bg1 + k0, &Bs[b][128 * 32 + tid * 8]);
    };
    auto stageA16 = [&](int k0, int b) {
        GLDS(Ag16 + k0, &As[b][tid * 8]);
    };

    // prologue
    stageB(0, 0);
    float a0[8];
    if (A_F32) {
        #pragma unroll
        for (int u = 0; u < 8; u++) a0[u] = Ag32[u];
        usx8 w;
        #pragma unroll
        for (int u = 0; u < 8; u++) w[u] = f2bf(a0[u]);
        *(usx8*)&As[0][tid * 8] = w;
    } else {
        stageA16(0, 0);
    }

    int buf = 0;
    for (int k = 0; k < nIter; ++k) {
        __syncthreads();   // buf ready (vm+lgkm drained); buf^1 reads done

        float anext[8];
        const bool more = (k + 1 < nIter);
        if (more) {
            const int ko = (k + 1) * 32;
            stageB(ko, buf ^ 1);
            if (A_F32) {
                #pragma unroll
                for (int u = 0; u < 8; u++) anext[u] = Ag32[ko + u];
            } else {
                stageA16(ko, buf ^ 1);
            }
        }

        bf16x8 af[4], bfr[4];
        #pragma unroll
        for (int i = 0; i < 4; i++)
            af[i] = *(const bf16x8*)&As[buf][(wr * 64 + i * 16 + r16) * 32 + quad * 8];
        #pragma unroll
        for (int j = 0; j < 4; j++)
            bfr[j] = *(const bf16x8*)&Bs[buf][(wc * 64 + j * 16 + r16) * 32 + quad * 8];

        #pragma unroll
        for (int i = 0; i < 4; i++)
            #pragma unroll
            for (int j = 0; j < 4; j++)
                acc[i][j] = __builtin_amdgcn_mfma_f32_16x16x32_bf16(
                                bfr[j], af[i], acc[i][j], 0, 0, 0);  // swapped

        if (A_F32 && more) {
            usx8 w;
            #pragma unroll
            for (int u = 0; u < 8; u++) w[u] = f2bf(anext[u]);
            *(usx8*)&As[buf ^ 1][tid * 8] = w;
        }
        buf ^= 1;
    }

    // epilogue: m = lane&15 (per i-tile), n = quad*4 + reg
    #pragma unroll
    for (int i = 0; i < 4; i++) {
        const int m = bm * 128 + wr * 64 + i * 16 + r16;
        #pragma unroll
        for (int j = 0; j < 4; j++) {
            const int n0 = bn * 256 + wc * 64 + j * 16 + quad * 4;
            const float4 bv = *(const float4*)&bias[n0];
            float v0 = acc[i][j][0] + bv.x;
            float v1 = acc[i][j][1] + bv.y;
            float v2 = acc[i][j][2] + bv.z;
            float v3 = acc[i][j][3] + bv.w;
            size_t idx = (size_t)m * N + n0;
            if (OUT_BF16) {
                ushort4 r;
                r.x = f2bf(v0); r.y = f2bf(v1); r.z = f2bf(v2); r.w = f2bf(v3);
                *(ushort4*)&((ushort*)Cout)[idx] = r;
            } else {
                *(float4*)&((float*)Cout)[idx] = make_float4(v0, v1, v2, v3);
            }
        }
    }
}

// ---------------- chunked linear-recurrence scan ----------------
// z[t] = c*z[t-1] + alpha*(xp[t]-xp[t-1]),  z[-1]=xp[-1]=init_state[h,dh]
// Each thread owns 2 adjacent channels (bf16x2 = uint loads/stores).
template <bool WRITE_Z>
__global__ void scan_kernel(const ushort* __restrict__ xp,
                            const float* __restrict__ alpha_param,
                            const float* __restrict__ init_state,
                            const float* __restrict__ Zin,
                            float* __restrict__ Lfin,
                            ushort* __restrict__ zout)
{
    const int tid   = threadIdx.x;
    const int chunk = blockIdx.x;          // 0..NCHUNK-1
    const int b     = blockIdx.y;          // 0..3
    const int d0    = tid * 2;             // 0..510 ; d = h*64+dh
    const int h     = d0 >> 6;

    const float alpha = 1.0f / (1.0f + expf(-alpha_param[h]));
    const float cdec  = 1.0f - alpha;
    const int   t0    = chunk * CHUNK;
    const size_t baseRow = (size_t)b * SEQ;
    const int ch0 = b * DIM + d0;

    float prev0, prev1;
    if (chunk == 0) {
        prev0 = init_state[d0]; prev1 = init_state[d0 + 1];
    } else {
        uint u = *(const uint*)&xp[(baseRow + t0 - 1) * DIM + d0];
        prev0 = bf2f((ushort)(u & 0xffffu)); prev1 = bf2f((ushort)(u >> 16));
    }
    float z0 = 0.f, z1 = 0.f;
    if (WRITE_Z) {
        z0 = Zin[(size_t)ch0 * NCHUNK + chunk];
        z1 = Zin[(size_t)(ch0 + 1) * NCHUNK + chunk];
    }

    const ushort* p = xp + (baseRow + t0) * DIM + d0;
    ushort* q = WRITE_Z ? (zout + (baseRow + t0) * DIM + d0) : nullptr;
    #pragma unroll 8
    for (int t = 0; t < CHUNK; ++t) {
        uint u = *(const uint*)&p[(size_t)t * DIM];
        float cur0 = bf2f((ushort)(u & 0xffffu));
        float cur1 = bf2f((ushort)(u >> 16));
        z0 = cdec * z0 + alpha * (cur0 - prev0);
        z1 = cdec * z1 + alpha * (cur1 - prev1);
        prev0 = cur0; prev1 = cur1;
        if (WRITE_Z) {
            uint w = (uint)f2bf(z0) | ((uint)f2bf(z1) << 16);
            *(uint*)&q[(size_t)t * DIM] = w;
        }
    }
    if (!WRITE_Z) {
        Lfin[(size_t)ch0 * NCHUNK + chunk]       = z0;
        Lfin[(size_t)(ch0 + 1) * NCHUNK + chunk] = z1;
    }
}

// Phase B: per-channel carry scan across the NCHUNK chunks.
__global__ void scan_fix_kernel(const float* __restrict__ Lfin,
                                const float* __restrict__ alpha_param,
                                const float* __restrict__ init_state,
                                float* __restrict__ Zin)
{
    int ch = blockIdx.x * blockDim.x + threadIdx.x;   // 0..2047 = b*512+d
    if (ch >= NCHAN) return;
    int d = ch & (DIM - 1);
    int h = d >> 6;
    float alpha = 1.0f / (1.0f + expf(-alpha_param[h]));
    float c = 1.0f - alpha;
    float cT = c;
    #pragma unroll
    for (int i = 0; i < 6; i++) cT *= cT;             // c^64, exact squarings
    float Z = init_state[d];
    const float* L = Lfin + (size_t)ch * NCHUNK;
    float*      Zp = Zin  + (size_t)ch * NCHUNK;
    for (int i = 0; i < NCHUNK; i++) { Zp[i] = Z; Z = L[i] + cT * Z; }
}

extern "C" void kernel_launch(void* const* d_in, const int* in_sizes, int n_in,
                              void* d_out, int out_size, void* d_ws, size_t ws_size,
                              hipStream_t stream) {
    const float* x           = (const float*)d_in[0];
    const float* W_in        = (const float*)d_in[1];
    const float* b_in        = (const float*)d_in[2];
    const float* W_out       = (const float*)d_in[3];
    const float* b_out       = (const float*)d_in[4];
    const float* init_state  = (const float*)d_in[5];
    const float* alpha_param = (const float*)d_in[6];
    float* out = (float*)d_out;

    // workspace layout (ushort units)
    ushort* z_bf    = (ushort*)d_ws;                        // 16,777,216
    ushort* win_bf  = z_bf   + (size_t)MROWS * DIM;         //    262,144
    ushort* wout_bf = win_bf + (size_t)DIM * DIM;           //    262,144
    ushort* xp_bf   = wout_bf + (size_t)DIM * DIM;          // 16,777,216
    float*  Lfin    = (float*)(xp_bf + (size_t)MROWS * DIM);
    float*  Zin     = Lfin + (size_t)NCHAN * NCHUNK;

    const int nw4 = (DIM * DIM) / 4;          //    65,536
    weights_to_bf16_kernel<<<(2 * nw4 + 255) / 256, 256, 0, stream>>>(
        W_in, W_out, win_bf, nw4);

    dim3 ggrid(DIM / 256, MROWS / 128);       // (2, 256)
    // GEMM1: A = x (fp32, converted in-staging), out = xp (bf16)
    gemm_kernel<true, true><<<ggrid, 512, 0, stream>>>(
        (const void*)x, win_bf, b_in, (void*)xp_bf, MROWS, DIM, DIM);

    dim3 sgrid(NCHUNK, BATCH);                // (128, 4)
    scan_kernel<false><<<sgrid, 256, 0, stream>>>(
        xp_bf, alpha_param, init_state, nullptr, Lfin, nullptr);
    scan_fix_kernel<<<NCHAN / 256, 256, 0, stream>>>(
        Lfin, alpha_param, init_state, Zin);
    scan_kernel<true><<<sgrid, 256, 0, stream>>>(
        xp_bf, alpha_param, init_state, Zin, nullptr, z_bf);

    // GEMM2: A = z (bf16), out = fp32
    gemm_kernel<false, false><<<ggrid, 512, 0, stream>>>(
        (const void*)z_bf, wout_bf, b_out, (void*)out, MROWS, DIM, DIM);
}